// Round 8
// baseline (3826.042 us; speedup 1.0000x reference)
//
#include <hip/hip_runtime.h>

// Problem dims (fixed by setup_inputs): T=256, B=64, I=512, H=2048
#define T_DIM 256
#define B_DIM 64
#define I_DIM 512
#define H_DIM 2048
#define BH (B_DIM * H_DIM)      // 131072 floats per timestep slice
#define NBLK 256                // persistent grid: 1 block per CU
#define PUB_U64 32768           // one parity: 16384 slots * 2 u64 (256 KB)
#define MASTER_OFF 4096         // u32 index of master flag in slots region

typedef __attribute__((ext_vector_type(8))) short bf16x8;
typedef __attribute__((ext_vector_type(4))) float f32x4;

// ---------------------------------------------------------------------
// Agent-scope ops (validated R4-R7): write-through stores visible at the
// device coherence point; polls are uncached fabric transactions (hence
// the R8 low-poller barrier); normal loads + per-step acquire fence
// (L1/L2 inv) give cross-XCD read sharing with L2 dedup.
// ---------------------------------------------------------------------
__device__ __forceinline__ unsigned aloadU32(const unsigned* p) {
  return __hip_atomic_load(p, __ATOMIC_RELAXED, __HIP_MEMORY_SCOPE_AGENT);
}
__device__ __forceinline__ void astore4(float* p, float a) {
  union { unsigned u; float f; } c; c.f = a;
  __hip_atomic_store((unsigned*)p, c.u, __ATOMIC_RELAXED,
                     __HIP_MEMORY_SCOPE_AGENT);
}
__device__ __forceinline__ void astoreU(unsigned long long* p,
                                        unsigned long long v) {
  __hip_atomic_store(p, v, __ATOMIC_RELAXED, __HIP_MEMORY_SCOPE_AGENT);
}

// bf16 split helpers
__device__ __forceinline__ unsigned bf16_rne(float x) {
  union { float f; unsigned u; } c; c.f = x;
  return (c.u + 0x7FFFu + ((c.u >> 16) & 1u)) >> 16;
}
__device__ __forceinline__ float bf16_to_f(unsigned b) {
  union { float f; unsigned u; } c; c.u = b << 16; return c.f;
}
__device__ __forceinline__ void cvt_pair(float x0, float x1,
                                         unsigned& hi, unsigned& lo) {
  unsigned h0 = bf16_rne(x0), h1 = bf16_rne(x1);
  float r0 = x0 - bf16_to_f(h0), r1 = x1 - bf16_to_f(h1);
  unsigned l0 = bf16_rne(r0), l1 = bf16_rne(r1);
  hi = h0 | (h1 << 16);
  lo = l0 | (l1 << 16);
}
__device__ __forceinline__ void cvt8(const float* s, uint4& hi, uint4& lo) {
  float4 a = *(const float4*)s;
  float4 b = *(const float4*)(s + 4);
  cvt_pair(a.x, a.y, hi.x, lo.x);
  cvt_pair(a.z, a.w, hi.y, lo.y);
  cvt_pair(b.x, b.y, hi.z, lo.z);
  cvt_pair(b.z, b.w, hi.w, lo.w);
}

// =====================================================================
// Kernel A: xin = x @ W_ih^T + b_ih + b_hh  (rows m<64 fold t=0:
// out[0] = 0.01*relu(xin[0])).  Unchanged (fp32 VALU, ~380us).
// =====================================================================
__global__ __launch_bounds__(256) void xin_gemm(
    const float* __restrict__ x, const float* __restrict__ Wih,
    const float* __restrict__ bih, const float* __restrict__ bhh,
    float* __restrict__ out)
{
  __shared__ __align__(16) float As[16][132];
  __shared__ __align__(16) float Bs[16][132];
  const int tid = threadIdx.x;
  const int nb = blockIdx.x & 15, mb = blockIdx.x >> 4;
  const int m0 = mb * 128, n0 = nb * 128;
  const int tx = tid & 15, ty = tid >> 4;

  float acc[8][8];
  #pragma unroll
  for (int i = 0; i < 8; ++i)
    #pragma unroll
    for (int j = 0; j < 8; ++j) acc[i][j] = 0.f;

  for (int k0 = 0; k0 < I_DIM; k0 += 16) {
    __syncthreads();
    {
      const int r = tid >> 1;
      #pragma unroll
      for (int c = 0; c < 2; ++c) {
        const int kq = (tid & 1) * 4 + c * 8;
        float4 va = *(const float4*)&x[(size_t)(m0 + r) * I_DIM + k0 + kq];
        As[kq + 0][r] = va.x; As[kq + 1][r] = va.y;
        As[kq + 2][r] = va.z; As[kq + 3][r] = va.w;
        float4 vb = *(const float4*)&Wih[(size_t)(n0 + r) * I_DIM + k0 + kq];
        Bs[kq + 0][r] = vb.x; Bs[kq + 1][r] = vb.y;
        Bs[kq + 2][r] = vb.z; Bs[kq + 3][r] = vb.w;
      }
    }
    __syncthreads();
    #pragma unroll 4
    for (int k = 0; k < 16; ++k) {
      float a[8], b[8];
      *(float4*)&a[0] = *(const float4*)&As[k][ty * 8];
      *(float4*)&a[4] = *(const float4*)&As[k][ty * 8 + 4];
      *(float4*)&b[0] = *(const float4*)&Bs[k][tx * 4];
      *(float4*)&b[4] = *(const float4*)&Bs[k][64 + tx * 4];
      #pragma unroll
      for (int i = 0; i < 8; ++i)
        #pragma unroll
        for (int j = 0; j < 8; ++j) acc[i][j] += a[i] * b[j];
    }
  }

  float bb[8];
  #pragma unroll
  for (int j = 0; j < 4; ++j) {
    bb[j]     = bih[n0 + tx * 4 + j]      + bhh[n0 + tx * 4 + j];
    bb[4 + j] = bih[n0 + 64 + tx * 4 + j] + bhh[n0 + 64 + tx * 4 + j];
  }
  #pragma unroll
  for (int i = 0; i < 8; ++i) {
    const int m = m0 + ty * 8 + i;
    float v[8];
    #pragma unroll
    for (int j = 0; j < 8; ++j) v[j] = acc[i][j] + bb[j];
    if (m < B_DIM) {
      #pragma unroll
      for (int j = 0; j < 8; ++j) v[j] = 0.01f * fmaxf(v[j], 0.f);
    }
    *(float4*)&out[(size_t)m * H_DIM + n0 + tx * 4] =
        make_float4(v[0], v[1], v[2], v[3]);
    *(float4*)&out[(size_t)m * H_DIM + n0 + 64 + tx * 4] =
        make_float4(v[4], v[5], v[6], v[7]);
  }
}

// ---------------------------------------------------------------------
// R8 two-hop low-congestion grid barrier.
// Arrival: per-block relaxed slot store (64B-spaced).
// Aggregate: block 0 wave 0 (64 lanes x 4 slots), __all-reduce, one
//            master store. Everyone else: ONE thread polls master; all
//            other threads wait at __syncthreads (zero fabric traffic).
// Poll population ~320 (was 65536) -> no MALL congestion.
// ---------------------------------------------------------------------
__device__ __forceinline__ void gbar(unsigned* slots, unsigned m, int bid) {
  asm volatile("s_waitcnt vmcnt(0) lgkmcnt(0)" ::: "memory");
  __syncthreads();
  if (threadIdx.x == 0)
    __hip_atomic_store(slots + (size_t)bid * 16, m, __ATOMIC_RELAXED,
                       __HIP_MEMORY_SCOPE_AGENT);
  unsigned* master = slots + MASTER_OFF;
  if (bid == 0) {
    if (threadIdx.x < 64) {
      const unsigned* s0 = slots + (size_t)threadIdx.x * 16;
      bool done = false;
      for (int it = 0; it < (1 << 15) && !done; ++it) {
        const unsigned a = aloadU32(s0);
        const unsigned b = aloadU32(s0 + 64 * 16);
        const unsigned c = aloadU32(s0 + 128 * 16);
        const unsigned d = aloadU32(s0 + 192 * 16);
        done = __all((a >= m) & (b >= m) & (c >= m) & (d >= m));
        if (!done) __builtin_amdgcn_s_sleep(1);
      }
      if (threadIdx.x == 0)
        __hip_atomic_store(master, m, __ATOMIC_RELAXED,
                           __HIP_MEMORY_SCOPE_AGENT);
    }
    __syncthreads();
  } else {
    if (threadIdx.x == 0) {
      for (int it = 0; it < (1 << 17); ++it) {
        if (aloadU32(master) >= m) break;
        __builtin_amdgcn_s_sleep(1);
      }
    }
    __syncthreads();
  }
}

// =====================================================================
// Kernel B: ONE-barrier-per-step persistent scan (structure = R7).
// 256 blocks x 256 thr (4 waves). Block (bh,nb) owns b in [bh*32,+32),
// n in [nb*16,+16), FULL K=2048. W slice (16n x 2048k, split-bf16 hi+lo)
// in LDS forever (128 KB). h operand: double-buffered global pub buffer
// of bf16 MFMA-A fragments -> consumers load A-frags DIRECTLY
// global->VGPR (L2-dedup'd per XCD after per-step acquire fence).
// Waves split K (4 x 512), cross-wave LDS reduce, fp32 register h
// update, astore out[t], publish bf16 h[t] to other parity. One gbar.
// =====================================================================
__global__ __launch_bounds__(256) void ctrnn_scan(
    const float* __restrict__ Whh, float* out,
    unsigned long long* __restrict__ pub, unsigned* slots)
{
  __shared__ __align__(16) uint4 Whi[4096];   // 64 KB
  __shared__ __align__(16) uint4 Wlo[4096];   // 64 KB
  __shared__ __align__(16) f32x4 Red[512];    // 8 KB
  __shared__ unsigned short Hs[32][16];       // 1 KB bf16 publish staging

  const int tid = threadIdx.x, bid = blockIdx.x;
  const int nb = bid & 127, bh = bid >> 7;
  const int n0 = nb * 16, b0 = bh * 32;

  const int lane = tid & 63, wid = tid >> 6;
  const int fq = lane >> 4, fr = lane & 15;

  // ---- stage W slice ONCE: rows n0..n0+16, all k, frag-packed hi/lo ----
  for (int s = tid; s < 4096; s += 256) {
    const int kcg = s >> 6, l = s & 63;
    const int n = n0 + (l & 15), k = kcg * 32 + (l >> 4) * 8;
    uint4 hi, lo;
    cvt8(&Whh[(size_t)n * H_DIM + k], hi, lo);
    Whi[s] = hi; Wlo[s] = lo;
  }

  // ---- ownership mapping (MFMA C layout: col=lane&15=n, row=b) ----
  const int bt = tid >> 7, jh = (tid >> 6) & 1, ln = tid & 63;
  const int rfr = ln & 15, rfq = ln >> 4;
  const int bl0 = bt * 16 + rfq * 4 + jh * 2;            // local b of 1st
  const size_t oa0 = (size_t)(b0 + bl0) * H_DIM + n0 + rfr;
  const size_t oa1 = oa0 + H_DIM;

  // fp32 h state in registers (h[0] = out[0], t=0 folded in xin_gemm)
  float h0 = out[oa0];
  float h1 = out[oa1];

  // ---- publish h[0] as bf16 frags to pub parity 0 ----
  Hs[bl0][rfr]     = (unsigned short)bf16_rne(h0);
  Hs[bl0 + 1][rfr] = (unsigned short)bf16_rne(h1);
  __syncthreads();   // also covers W staging completion
  if (tid < 64) {
    const int b_l = tid & 31, h8 = tid >> 5;
    const uint4 frag = *(const uint4*)&Hs[b_l][h8 * 8];
    const size_t slot = (size_t)(nb * 2 + h8) * 64 + b0 + b_l;
    astoreU(&pub[slot * 2 + 0], ((const unsigned long long*)&frag)[0]);
    astoreU(&pub[slot * 2 + 1], ((const unsigned long long*)&frag)[1]);
  }

  const int baseA = wid * 4096 + fq * 64 + b0 + fr;  // slot idx, +kc*256
  const int baseB = wid * 1024;                      // +kc*64+lane

  for (int t = 1; t < T_DIM; ++t) {
    // prefetch xin BEFORE barrier (written by xin_gemm pre-launch; lines
    // never previously cached by this CU -> no staleness; latency hides
    // under the barrier wait).
    const float xin0 = out[(size_t)t * BH + oa0];
    const float xin1 = out[(size_t)t * BH + oa1];
    asm volatile("" :: "v"(xin0), "v"(xin1));  // keep loads before gbar

    gbar(slots, t, bid);   // vmcnt(0) inside drains publishes first
    __builtin_amdgcn_fence(__ATOMIC_ACQUIRE, "agent");  // L1/L2 inv

    const uint4* pr = (const uint4*)(pub + (size_t)((t - 1) & 1) * PUB_U64);

    // ---- GEMM: this wave covers k in [wid*512, +512) ----
    f32x4 acc0 = {0.f, 0.f, 0.f, 0.f}, acc1 = {0.f, 0.f, 0.f, 0.f};
    #pragma unroll
    for (int kc = 0; kc < 16; ++kc) {
      const uint4 a0 = pr[baseA + kc * 256];        // A-frag, btile 0
      const uint4 a1 = pr[baseA + kc * 256 + 16];   // A-frag, btile 1
      const uint4 bh4 = Whi[baseB + kc * 64 + lane];
      const uint4 bl4 = Wlo[baseB + kc * 64 + lane];
      acc0 = __builtin_amdgcn_mfma_f32_16x16x32_bf16(
          *(const bf16x8*)&a0, *(const bf16x8*)&bh4, acc0, 0, 0, 0);
      acc0 = __builtin_amdgcn_mfma_f32_16x16x32_bf16(
          *(const bf16x8*)&a0, *(const bf16x8*)&bl4, acc0, 0, 0, 0);
      acc1 = __builtin_amdgcn_mfma_f32_16x16x32_bf16(
          *(const bf16x8*)&a1, *(const bf16x8*)&bh4, acc1, 0, 0, 0);
      acc1 = __builtin_amdgcn_mfma_f32_16x16x32_bf16(
          *(const bf16x8*)&a1, *(const bf16x8*)&bl4, acc1, 0, 0, 0);
    }

    // ---- cross-wave K reduce ----
    Red[(wid * 2 + 0) * 64 + lane] = acc0;
    Red[(wid * 2 + 1) * 64 + lane] = acc1;
    __syncthreads();

    float s0 = 0.f, s1 = 0.f;
    #pragma unroll
    for (int w = 0; w < 4; ++w) {
      const float2 p = *(const float2*)(
          (const char*)&Red[(w * 2 + bt) * 64 + ln] + jh * 8);
      s0 += p.x; s1 += p.y;
    }

    // ---- leaky-relu update (fp32 register state) ----
    h0 = 0.99f * h0 + 0.01f * fmaxf(xin0 + s0, 0.f);
    h1 = 0.99f * h1 + 0.01f * fmaxf(xin1 + s1, 0.f);

    // ---- publish bf16 h[t] first (critical path), then out stores ----
    __syncthreads();   // Red reads done; safe to reuse Hs
    Hs[bl0][rfr]     = (unsigned short)bf16_rne(h0);
    Hs[bl0 + 1][rfr] = (unsigned short)bf16_rne(h1);
    __syncthreads();
    if (tid < 64) {
      const int b_l = tid & 31, h8 = tid >> 5;
      const uint4 frag = *(const uint4*)&Hs[b_l][h8 * 8];
      const size_t slot = (size_t)(nb * 2 + h8) * 64 + b0 + b_l;
      unsigned long long* pw =
          pub + (size_t)(t & 1) * PUB_U64 + slot * 2;
      astoreU(pw + 0, ((const unsigned long long*)&frag)[0]);
      astoreU(pw + 1, ((const unsigned long long*)&frag)[1]);
    }
    astore4(&out[(size_t)t * BH + oa0], h0);
    astore4(&out[(size_t)t * BH + oa1], h1);
    if (t == T_DIM - 1) {
      astore4(&out[(size_t)T_DIM * BH + oa0], h0);  // h_last
      astore4(&out[(size_t)T_DIM * BH + oa1], h1);
    }
    // next gbar's vmcnt(0) drains publishes before signaling
  }
}

// =====================================================================
extern "C" void kernel_launch(void* const* d_in, const int* in_sizes, int n_in,
                              void* d_out, int out_size, void* d_ws, size_t ws_size,
                              hipStream_t stream) {
  const float* x    = (const float*)d_in[0];
  const float* Wih  = (const float*)d_in[1];
  const float* bih  = (const float*)d_in[2];
  const float* Whh  = (const float*)d_in[3];
  const float* bhh  = (const float*)d_in[4];
  float* out = (float*)d_out;

  unsigned* slots = (unsigned*)d_ws;                          // 16KB + master
  unsigned long long* pub =
      (unsigned long long*)((char*)d_ws + 32768);             // 512 KB

  hipMemsetAsync(d_ws, 0, 32768, stream);  // reset slots+master every call

  xin_gemm<<<dim3(2048), dim3(256), 0, stream>>>(x, Wih, bih, bhh, out);
  ctrnn_scan<<<dim3(NBLK), dim3(256), 0, stream>>>(Whh, out, pub, slots);
}

// Round 9
// 3683.827 us; speedup vs baseline: 1.0386x; 1.0386x over previous
//
#include <hip/hip_runtime.h>

// Problem dims (fixed by setup_inputs): T=256, B=64, I=512, H=2048
#define T_DIM 256
#define B_DIM 64
#define I_DIM 512
#define H_DIM 2048
#define BH (B_DIM * H_DIM)      // 131072 floats per timestep slice
#define NBLK 256                // persistent grid: 1 block per CU
#define PUB_U64 32768           // one parity: 16384 slots * 2 u64 (256 KB)
#define MASTER_OFF 4096         // u32 index of master flag in slots region

typedef __attribute__((ext_vector_type(8))) short bf16x8;
typedef __attribute__((ext_vector_type(4))) float f32x4;

// ---------------------------------------------------------------------
// Agent-scope ops (validated R4-R8): write-through stores visible at the
// device coherence point; normal loads + per-step acquire fence (L1/L2
// inv) give cross-XCD read sharing with L2 dedup.
// ---------------------------------------------------------------------
__device__ __forceinline__ unsigned aloadU32(const unsigned* p) {
  return __hip_atomic_load(p, __ATOMIC_RELAXED, __HIP_MEMORY_SCOPE_AGENT);
}
__device__ __forceinline__ void astore4(float* p, float a) {
  union { unsigned u; float f; } c; c.f = a;
  __hip_atomic_store((unsigned*)p, c.u, __ATOMIC_RELAXED,
                     __HIP_MEMORY_SCOPE_AGENT);
}
__device__ __forceinline__ void astoreU(unsigned long long* p,
                                        unsigned long long v) {
  __hip_atomic_store(p, v, __ATOMIC_RELAXED, __HIP_MEMORY_SCOPE_AGENT);
}

// bf16 split helpers
__device__ __forceinline__ unsigned bf16_rne(float x) {
  union { float f; unsigned u; } c; c.f = x;
  return (c.u + 0x7FFFu + ((c.u >> 16) & 1u)) >> 16;
}
__device__ __forceinline__ float bf16_to_f(unsigned b) {
  union { float f; unsigned u; } c; c.u = b << 16; return c.f;
}
__device__ __forceinline__ void cvt_pair(float x0, float x1,
                                         unsigned& hi, unsigned& lo) {
  unsigned h0 = bf16_rne(x0), h1 = bf16_rne(x1);
  float r0 = x0 - bf16_to_f(h0), r1 = x1 - bf16_to_f(h1);
  unsigned l0 = bf16_rne(r0), l1 = bf16_rne(r1);
  hi = h0 | (h1 << 16);
  lo = l0 | (l1 << 16);
}
__device__ __forceinline__ void cvt8(const float* s, uint4& hi, uint4& lo) {
  float4 a = *(const float4*)s;
  float4 b = *(const float4*)(s + 4);
  cvt_pair(a.x, a.y, hi.x, lo.x);
  cvt_pair(a.z, a.w, hi.y, lo.y);
  cvt_pair(b.x, b.y, hi.z, lo.z);
  cvt_pair(b.z, b.w, hi.w, lo.w);
}

// =====================================================================
// Kernel A: xin = x @ W_ih^T + b_ih + b_hh  (rows m<64 fold t=0:
// out[0] = 0.01*relu(xin[0])).  Unchanged (fp32 VALU, ~380us).
// =====================================================================
__global__ __launch_bounds__(256) void xin_gemm(
    const float* __restrict__ x, const float* __restrict__ Wih,
    const float* __restrict__ bih, const float* __restrict__ bhh,
    float* __restrict__ out)
{
  __shared__ __align__(16) float As[16][132];
  __shared__ __align__(16) float Bs[16][132];
  const int tid = threadIdx.x;
  const int nb = blockIdx.x & 15, mb = blockIdx.x >> 4;
  const int m0 = mb * 128, n0 = nb * 128;
  const int tx = tid & 15, ty = tid >> 4;

  float acc[8][8];
  #pragma unroll
  for (int i = 0; i < 8; ++i)
    #pragma unroll
    for (int j = 0; j < 8; ++j) acc[i][j] = 0.f;

  for (int k0 = 0; k0 < I_DIM; k0 += 16) {
    __syncthreads();
    {
      const int r = tid >> 1;
      #pragma unroll
      for (int c = 0; c < 2; ++c) {
        const int kq = (tid & 1) * 4 + c * 8;
        float4 va = *(const float4*)&x[(size_t)(m0 + r) * I_DIM + k0 + kq];
        As[kq + 0][r] = va.x; As[kq + 1][r] = va.y;
        As[kq + 2][r] = va.z; As[kq + 3][r] = va.w;
        float4 vb = *(const float4*)&Wih[(size_t)(n0 + r) * I_DIM + k0 + kq];
        Bs[kq + 0][r] = vb.x; Bs[kq + 1][r] = vb.y;
        Bs[kq + 2][r] = vb.z; Bs[kq + 3][r] = vb.w;
      }
    }
    __syncthreads();
    #pragma unroll 4
    for (int k = 0; k < 16; ++k) {
      float a[8], b[8];
      *(float4*)&a[0] = *(const float4*)&As[k][ty * 8];
      *(float4*)&a[4] = *(const float4*)&As[k][ty * 8 + 4];
      *(float4*)&b[0] = *(const float4*)&Bs[k][tx * 4];
      *(float4*)&b[4] = *(const float4*)&Bs[k][64 + tx * 4];
      #pragma unroll
      for (int i = 0; i < 8; ++i)
        #pragma unroll
        for (int j = 0; j < 8; ++j) acc[i][j] += a[i] * b[j];
    }
  }

  float bb[8];
  #pragma unroll
  for (int j = 0; j < 4; ++j) {
    bb[j]     = bih[n0 + tx * 4 + j]      + bhh[n0 + tx * 4 + j];
    bb[4 + j] = bih[n0 + 64 + tx * 4 + j] + bhh[n0 + 64 + tx * 4 + j];
  }
  #pragma unroll
  for (int i = 0; i < 8; ++i) {
    const int m = m0 + ty * 8 + i;
    float v[8];
    #pragma unroll
    for (int j = 0; j < 8; ++j) v[j] = acc[i][j] + bb[j];
    if (m < B_DIM) {
      #pragma unroll
      for (int j = 0; j < 8; ++j) v[j] = 0.01f * fmaxf(v[j], 0.f);
    }
    *(float4*)&out[(size_t)m * H_DIM + n0 + tx * 4] =
        make_float4(v[0], v[1], v[2], v[3]);
    *(float4*)&out[(size_t)m * H_DIM + n0 + 64 + tx * 4] =
        make_float4(v[4], v[5], v[6], v[7]);
  }
}

// ---------------------------------------------------------------------
// R9 barrier: two-hop structure (R8) but HOT-SPIN waits that burn VALU
// to hold DVFS clocks up (R8 showed ~700 MHz idle-downclock was the
// floor: MfmaUtil 3.2% with fixed 307 MFMA-cyc/step implies f~700MHz).
// - arrival: per-block slot store (64B spaced).
// - acquire fence EARLY (before detect): L1/L2 inv overlaps the wait;
//   post-detect pub reads go straight to MALL. No cached pub lines can
//   exist between fence and detect (only agent polls in that window).
// - block 0 wave 0: polls 256 slots (4/lane) + 32-FMA burn per sweep,
//   then lane 0 stores master.
// - everyone: polls master (same-address coalesced per wave) + burn.
// No s_sleep anywhere. Burn regs feed a never-true store (DCE-proof).
// ---------------------------------------------------------------------
__device__ __forceinline__ void gbar(unsigned* slots, unsigned m, int bid) {
  asm volatile("s_waitcnt vmcnt(0) lgkmcnt(0)" ::: "memory");
  __syncthreads();
  if (threadIdx.x == 0)
    __hip_atomic_store(slots + (size_t)bid * 16, m, __ATOMIC_RELAXED,
                       __HIP_MEMORY_SCOPE_AGENT);
  __builtin_amdgcn_fence(__ATOMIC_ACQUIRE, "agent");  // inv during wait
  unsigned* master = slots + MASTER_OFF;
  float p0 = 1.00f, p1 = 1.05f, p2 = 1.10f, p3 = 1.15f;
  if (bid == 0 && (threadIdx.x >> 6) == 0) {
    const unsigned* s0 = slots + (size_t)(threadIdx.x & 63) * 16;
    for (int it = 0; it < (1 << 15); ++it) {
      const unsigned a = aloadU32(s0);
      const unsigned b = aloadU32(s0 + 64 * 16);
      const unsigned c = aloadU32(s0 + 128 * 16);
      const unsigned d = aloadU32(s0 + 192 * 16);
      if (__all((a >= m) & (b >= m) & (c >= m) & (d >= m))) break;
      #pragma unroll
      for (int i = 0; i < 8; ++i) {
        p0 = fmaf(p0, 0.9999999f, 1e-8f);
        p1 = fmaf(p1, 0.9999999f, 1e-8f);
        p2 = fmaf(p2, 0.9999999f, 1e-8f);
        p3 = fmaf(p3, 0.9999999f, 1e-8f);
      }
    }
    if ((threadIdx.x & 63) == 0)
      __hip_atomic_store(master, m, __ATOMIC_RELAXED,
                         __HIP_MEMORY_SCOPE_AGENT);
  }
  for (int it = 0; it < (1 << 17); ++it) {
    if (aloadU32(master) >= m) break;   // same addr all lanes: 1 txn/wave
    #pragma unroll
    for (int i = 0; i < 8; ++i) {
      p0 = fmaf(p0, 0.9999999f, 1e-8f);
      p1 = fmaf(p1, 0.9999999f, 1e-8f);
      p2 = fmaf(p2, 0.9999999f, 1e-8f);
      p3 = fmaf(p3, 0.9999999f, 1e-8f);
    }
  }
  if (p0 + p1 + p2 + p3 == 123456.789f)   // never true; keeps burn live
    __hip_atomic_store(master + 16, 1u, __ATOMIC_RELAXED,
                       __HIP_MEMORY_SCOPE_AGENT);
  __syncthreads();
}

// =====================================================================
// Kernel B: ONE-barrier-per-step persistent scan (dataflow = R7/R8).
// 256 blocks x 256 thr (4 waves). Block (bh,nb) owns b in [bh*32,+32),
// n in [nb*16,+16), FULL K=2048. W slice (16n x 2048k, split-bf16 hi+lo)
// in LDS forever (128 KB). h operand: double-buffered global pub buffer
// of bf16 MFMA-A fragments -> consumers load A-frags DIRECTLY
// global->VGPR (L2-dedup'd per XCD after the in-barrier acquire fence).
// Waves split K (4 x 512), cross-wave LDS reduce, fp32 register h
// update, astore out[t], publish bf16 h[t] to other parity. One gbar.
// =====================================================================
__global__ __launch_bounds__(256) void ctrnn_scan(
    const float* __restrict__ Whh, float* out,
    unsigned long long* __restrict__ pub, unsigned* slots)
{
  __shared__ __align__(16) uint4 Whi[4096];   // 64 KB
  __shared__ __align__(16) uint4 Wlo[4096];   // 64 KB
  __shared__ __align__(16) f32x4 Red[512];    // 8 KB
  __shared__ unsigned short Hs[32][16];       // 1 KB bf16 publish staging

  const int tid = threadIdx.x, bid = blockIdx.x;
  const int nb = bid & 127, bh = bid >> 7;
  const int n0 = nb * 16, b0 = bh * 32;

  const int lane = tid & 63, wid = tid >> 6;
  const int fq = lane >> 4, fr = lane & 15;

  // ---- stage W slice ONCE: rows n0..n0+16, all k, frag-packed hi/lo ----
  for (int s = tid; s < 4096; s += 256) {
    const int kcg = s >> 6, l = s & 63;
    const int n = n0 + (l & 15), k = kcg * 32 + (l >> 4) * 8;
    uint4 hi, lo;
    cvt8(&Whh[(size_t)n * H_DIM + k], hi, lo);
    Whi[s] = hi; Wlo[s] = lo;
  }

  // ---- ownership mapping (MFMA C layout: col=lane&15=n, row=b) ----
  const int bt = tid >> 7, jh = (tid >> 6) & 1, ln = tid & 63;
  const int rfr = ln & 15, rfq = ln >> 4;
  const int bl0 = bt * 16 + rfq * 4 + jh * 2;            // local b of 1st
  const size_t oa0 = (size_t)(b0 + bl0) * H_DIM + n0 + rfr;
  const size_t oa1 = oa0 + H_DIM;

  // fp32 h state in registers (h[0] = out[0], t=0 folded in xin_gemm)
  float h0 = out[oa0];
  float h1 = out[oa1];

  // ---- publish h[0] as bf16 frags to pub parity 0 ----
  Hs[bl0][rfr]     = (unsigned short)bf16_rne(h0);
  Hs[bl0 + 1][rfr] = (unsigned short)bf16_rne(h1);
  __syncthreads();   // also covers W staging completion
  if (tid < 64) {
    const int b_l = tid & 31, h8 = tid >> 5;
    const uint4 frag = *(const uint4*)&Hs[b_l][h8 * 8];
    const size_t slot = (size_t)(nb * 2 + h8) * 64 + b0 + b_l;
    astoreU(&pub[slot * 2 + 0], ((const unsigned long long*)&frag)[0]);
    astoreU(&pub[slot * 2 + 1], ((const unsigned long long*)&frag)[1]);
  }

  const int baseA = wid * 4096 + fq * 64 + b0 + fr;  // slot idx, +kc*256
  const int baseB = wid * 1024;                      // +kc*64+lane

  for (int t = 1; t < T_DIM; ++t) {
    // prefetch xin BEFORE barrier (latency hides under the wait; values
    // land in VGPRs before the in-barrier fence invalidates caches).
    const float xin0 = out[(size_t)t * BH + oa0];
    const float xin1 = out[(size_t)t * BH + oa1];
    asm volatile("" :: "v"(xin0), "v"(xin1));  // keep loads before gbar

    gbar(slots, t, bid);   // vmcnt(0) drain + early fence + hot-spin

    const uint4* pr = (const uint4*)(pub + (size_t)((t - 1) & 1) * PUB_U64);

    // ---- GEMM: this wave covers k in [wid*512, +512) ----
    f32x4 acc0 = {0.f, 0.f, 0.f, 0.f}, acc1 = {0.f, 0.f, 0.f, 0.f};
    #pragma unroll
    for (int kc = 0; kc < 16; ++kc) {
      const uint4 a0 = pr[baseA + kc * 256];        // A-frag, btile 0
      const uint4 a1 = pr[baseA + kc * 256 + 16];   // A-frag, btile 1
      const uint4 bh4 = Whi[baseB + kc * 64 + lane];
      const uint4 bl4 = Wlo[baseB + kc * 64 + lane];
      acc0 = __builtin_amdgcn_mfma_f32_16x16x32_bf16(
          *(const bf16x8*)&a0, *(const bf16x8*)&bh4, acc0, 0, 0, 0);
      acc0 = __builtin_amdgcn_mfma_f32_16x16x32_bf16(
          *(const bf16x8*)&a0, *(const bf16x8*)&bl4, acc0, 0, 0, 0);
      acc1 = __builtin_amdgcn_mfma_f32_16x16x32_bf16(
          *(const bf16x8*)&a1, *(const bf16x8*)&bh4, acc1, 0, 0, 0);
      acc1 = __builtin_amdgcn_mfma_f32_16x16x32_bf16(
          *(const bf16x8*)&a1, *(const bf16x8*)&bl4, acc1, 0, 0, 0);
    }

    // ---- cross-wave K reduce ----
    Red[(wid * 2 + 0) * 64 + lane] = acc0;
    Red[(wid * 2 + 1) * 64 + lane] = acc1;
    __syncthreads();

    float s0 = 0.f, s1 = 0.f;
    #pragma unroll
    for (int w = 0; w < 4; ++w) {
      const float2 p = *(const float2*)(
          (const char*)&Red[(w * 2 + bt) * 64 + ln] + jh * 8);
      s0 += p.x; s1 += p.y;
    }

    // ---- leaky-relu update (fp32 register state) ----
    h0 = 0.99f * h0 + 0.01f * fmaxf(xin0 + s0, 0.f);
    h1 = 0.99f * h1 + 0.01f * fmaxf(xin1 + s1, 0.f);

    // ---- publish bf16 h[t] first (critical path), then out stores ----
    __syncthreads();   // Red reads done; safe to reuse Hs
    Hs[bl0][rfr]     = (unsigned short)bf16_rne(h0);
    Hs[bl0 + 1][rfr] = (unsigned short)bf16_rne(h1);
    __syncthreads();
    if (tid < 64) {
      const int b_l = tid & 31, h8 = tid >> 5;
      const uint4 frag = *(const uint4*)&Hs[b_l][h8 * 8];
      const size_t slot = (size_t)(nb * 2 + h8) * 64 + b0 + b_l;
      unsigned long long* pw =
          pub + (size_t)(t & 1) * PUB_U64 + slot * 2;
      astoreU(pw + 0, ((const unsigned long long*)&frag)[0]);
      astoreU(pw + 1, ((const unsigned long long*)&frag)[1]);
    }
    astore4(&out[(size_t)t * BH + oa0], h0);
    astore4(&out[(size_t)t * BH + oa1], h1);
    if (t == T_DIM - 1) {
      astore4(&out[(size_t)T_DIM * BH + oa0], h0);  // h_last
      astore4(&out[(size_t)T_DIM * BH + oa1], h1);
    }
    // next gbar's vmcnt(0) drains publishes before signaling
  }
}

// =====================================================================
extern "C" void kernel_launch(void* const* d_in, const int* in_sizes, int n_in,
                              void* d_out, int out_size, void* d_ws, size_t ws_size,
                              hipStream_t stream) {
  const float* x    = (const float*)d_in[0];
  const float* Wih  = (const float*)d_in[1];
  const float* bih  = (const float*)d_in[2];
  const float* Whh  = (const float*)d_in[3];
  const float* bhh  = (const float*)d_in[4];
  float* out = (float*)d_out;

  unsigned* slots = (unsigned*)d_ws;                          // 16KB + master
  unsigned long long* pub =
      (unsigned long long*)((char*)d_ws + 32768);             // 512 KB

  hipMemsetAsync(d_ws, 0, 32768, stream);  // reset slots+master every call

  xin_gemm<<<dim3(2048), dim3(256), 0, stream>>>(x, Wih, bih, bhh, out);
  ctrnn_scan<<<dim3(NBLK), dim3(256), 0, stream>>>(Whh, out, pub, slots);
}

// Round 10
// 3454.057 us; speedup vs baseline: 1.1077x; 1.0665x over previous
//
#include <hip/hip_runtime.h>

// Problem dims (fixed by setup_inputs): T=256, B=64, I=512, H=2048
#define T_DIM 256
#define B_DIM 64
#define I_DIM 512
#define H_DIM 2048
#define BH (B_DIM * H_DIM)      // 131072 floats per timestep slice
#define NBLK 256                // persistent grid: 1 block per CU
#define PUB_U64 32768           // one parity: 16384 slots * 2 u64 (256 KB)
#define MASTER_OFF 4096         // u32 index of master flag in slots region

typedef __attribute__((ext_vector_type(8))) short bf16x8;
typedef __attribute__((ext_vector_type(4))) float f32x4;

// ---------------------------------------------------------------------
// Agent-scope ops (validated R4-R9): write-through stores visible at the
// device coherence point; normal loads + per-step acquire fence (L1/L2
// inv) give cross-XCD read sharing with L2 dedup.
// ---------------------------------------------------------------------
__device__ __forceinline__ unsigned aloadU32(const unsigned* p) {
  return __hip_atomic_load(p, __ATOMIC_RELAXED, __HIP_MEMORY_SCOPE_AGENT);
}
__device__ __forceinline__ void astore4(float* p, float a) {
  union { unsigned u; float f; } c; c.f = a;
  __hip_atomic_store((unsigned*)p, c.u, __ATOMIC_RELAXED,
                     __HIP_MEMORY_SCOPE_AGENT);
}
__device__ __forceinline__ void astoreU(unsigned long long* p,
                                        unsigned long long v) {
  __hip_atomic_store(p, v, __ATOMIC_RELAXED, __HIP_MEMORY_SCOPE_AGENT);
}

// bf16 split helpers
__device__ __forceinline__ unsigned bf16_rne(float x) {
  union { float f; unsigned u; } c; c.f = x;
  return (c.u + 0x7FFFu + ((c.u >> 16) & 1u)) >> 16;
}
__device__ __forceinline__ float bf16_to_f(unsigned b) {
  union { float f; unsigned u; } c; c.u = b << 16; return c.f;
}
__device__ __forceinline__ void cvt_pair(float x0, float x1,
                                         unsigned& hi, unsigned& lo) {
  unsigned h0 = bf16_rne(x0), h1 = bf16_rne(x1);
  float r0 = x0 - bf16_to_f(h0), r1 = x1 - bf16_to_f(h1);
  unsigned l0 = bf16_rne(r0), l1 = bf16_rne(r1);
  hi = h0 | (h1 << 16);
  lo = l0 | (l1 << 16);
}
__device__ __forceinline__ void cvt8(const float* s, uint4& hi, uint4& lo) {
  float4 a = *(const float4*)s;
  float4 b = *(const float4*)(s + 4);
  cvt_pair(a.x, a.y, hi.x, lo.x);
  cvt_pair(a.z, a.w, hi.y, lo.y);
  cvt_pair(b.x, b.y, hi.z, lo.z);
  cvt_pair(b.z, b.w, hi.w, lo.w);
}

// =====================================================================
// Kernel A: xin = x @ W_ih^T + b_ih + b_hh  (rows m<64 fold t=0:
// out[0] = 0.01*relu(xin[0])).  Unchanged (fp32 VALU).
// =====================================================================
__global__ __launch_bounds__(256) void xin_gemm(
    const float* __restrict__ x, const float* __restrict__ Wih,
    const float* __restrict__ bih, const float* __restrict__ bhh,
    float* __restrict__ out)
{
  __shared__ __align__(16) float As[16][132];
  __shared__ __align__(16) float Bs[16][132];
  const int tid = threadIdx.x;
  const int nb = blockIdx.x & 15, mb = blockIdx.x >> 4;
  const int m0 = mb * 128, n0 = nb * 128;
  const int tx = tid & 15, ty = tid >> 4;

  float acc[8][8];
  #pragma unroll
  for (int i = 0; i < 8; ++i)
    #pragma unroll
    for (int j = 0; j < 8; ++j) acc[i][j] = 0.f;

  for (int k0 = 0; k0 < I_DIM; k0 += 16) {
    __syncthreads();
    {
      const int r = tid >> 1;
      #pragma unroll
      for (int c = 0; c < 2; ++c) {
        const int kq = (tid & 1) * 4 + c * 8;
        float4 va = *(const float4*)&x[(size_t)(m0 + r) * I_DIM + k0 + kq];
        As[kq + 0][r] = va.x; As[kq + 1][r] = va.y;
        As[kq + 2][r] = va.z; As[kq + 3][r] = va.w;
        float4 vb = *(const float4*)&Wih[(size_t)(n0 + r) * I_DIM + k0 + kq];
        Bs[kq + 0][r] = vb.x; Bs[kq + 1][r] = vb.y;
        Bs[kq + 2][r] = vb.z; Bs[kq + 3][r] = vb.w;
      }
    }
    __syncthreads();
    #pragma unroll 4
    for (int k = 0; k < 16; ++k) {
      float a[8], b[8];
      *(float4*)&a[0] = *(const float4*)&As[k][ty * 8];
      *(float4*)&a[4] = *(const float4*)&As[k][ty * 8 + 4];
      *(float4*)&b[0] = *(const float4*)&Bs[k][tx * 4];
      *(float4*)&b[4] = *(const float4*)&Bs[k][64 + tx * 4];
      #pragma unroll
      for (int i = 0; i < 8; ++i)
        #pragma unroll
        for (int j = 0; j < 8; ++j) acc[i][j] += a[i] * b[j];
    }
  }

  float bb[8];
  #pragma unroll
  for (int j = 0; j < 4; ++j) {
    bb[j]     = bih[n0 + tx * 4 + j]      + bhh[n0 + tx * 4 + j];
    bb[4 + j] = bih[n0 + 64 + tx * 4 + j] + bhh[n0 + 64 + tx * 4 + j];
  }
  #pragma unroll
  for (int i = 0; i < 8; ++i) {
    const int m = m0 + ty * 8 + i;
    float v[8];
    #pragma unroll
    for (int j = 0; j < 8; ++j) v[j] = acc[i][j] + bb[j];
    if (m < B_DIM) {
      #pragma unroll
      for (int j = 0; j < 8; ++j) v[j] = 0.01f * fmaxf(v[j], 0.f);
    }
    *(float4*)&out[(size_t)m * H_DIM + n0 + tx * 4] =
        make_float4(v[0], v[1], v[2], v[3]);
    *(float4*)&out[(size_t)m * H_DIM + n0 + 64 + tx * 4] =
        make_float4(v[4], v[5], v[6], v[7]);
  }
}

// ---------------------------------------------------------------------
// R10 barrier: two-hop detection (wave 0) + DVFS-defeating burner waves.
// R9's failure mode: poll-load latency (~1us) dwarfed the 32-FMA burn ->
// VALUBusy stayed 3.5% -> governor kept ~750 MHz core clock (MfmaUtil
// arithmetic, R8/R9). Fix: waves 1-3 burn 256 straight-line FMAs per
// sweep (8 indep chains, ~81% issue duty), exit via LDS 'go' flag posted
// by wave 0 (zero fabric traffic). Wave 0 does all fabric detection:
// block0 sweeps 256 slots (4/lane), others single-lane master poll.
// ---------------------------------------------------------------------
__device__ __forceinline__ void gbar(unsigned* slots, unsigned m, int bid,
                                     volatile unsigned* go) {
  asm volatile("s_waitcnt vmcnt(0) lgkmcnt(0)" ::: "memory");
  __syncthreads();
  const int tid = threadIdx.x;
  if (tid == 0)
    __hip_atomic_store(slots + (size_t)bid * 16, m, __ATOMIC_RELAXED,
                       __HIP_MEMORY_SCOPE_AGENT);
  __builtin_amdgcn_fence(__ATOMIC_ACQUIRE, "agent");  // inv during wait
  unsigned* master = slots + MASTER_OFF;
  if (tid < 64) {
    // ---- wave 0: detection duty (SIMD 0; not burning) ----
    if (bid == 0) {
      const unsigned* s0 = slots + (size_t)tid * 16;
      for (int it = 0; it < (1 << 17); ++it) {
        const unsigned a = aloadU32(s0);
        const unsigned b = aloadU32(s0 + 64 * 16);
        const unsigned c = aloadU32(s0 + 128 * 16);
        const unsigned d = aloadU32(s0 + 192 * 16);
        if (__all((a >= m) & (b >= m) & (c >= m) & (d >= m))) break;
        __builtin_amdgcn_s_sleep(1);
      }
      if (tid == 0)
        __hip_atomic_store(master, m, __ATOMIC_RELAXED,
                           __HIP_MEMORY_SCOPE_AGENT);
    } else if (tid == 0) {
      for (int it = 0; it < (1 << 17); ++it) {
        if (aloadU32(master) >= m) break;
        __builtin_amdgcn_s_sleep(1);
      }
    }
    if (tid == 0) *go = m;   // LDS release to burners
  } else {
    // ---- waves 1-3: hot-burn FMAs (holds DVFS clocks up) ----
    float a0 = 1.00f, a1 = 1.05f, a2 = 1.10f, a3 = 1.15f;
    float a4 = 1.20f, a5 = 1.25f, a6 = 1.30f, a7 = 1.35f;
    for (int it = 0; it < 8192; ++it) {
      #pragma unroll
      for (int i = 0; i < 32; ++i) {     // 256 FMAs straight-line
        a0 = fmaf(a0, 0.9999999f, 1e-8f);
        a1 = fmaf(a1, 0.9999999f, 1e-8f);
        a2 = fmaf(a2, 0.9999999f, 1e-8f);
        a3 = fmaf(a3, 0.9999999f, 1e-8f);
        a4 = fmaf(a4, 0.9999999f, 1e-8f);
        a5 = fmaf(a5, 0.9999999f, 1e-8f);
        a6 = fmaf(a6, 0.9999999f, 1e-8f);
        a7 = fmaf(a7, 0.9999999f, 1e-8f);
      }
      if (*go >= m) break;               // LDS read: no fabric traffic
    }
    asm volatile("" :: "v"(a0), "v"(a1), "v"(a2), "v"(a3),
                       "v"(a4), "v"(a5), "v"(a6), "v"(a7));  // DCE-proof
  }
  __syncthreads();
}

// =====================================================================
// Kernel B: ONE-barrier-per-step persistent scan (dataflow = R7/R8/R9).
// 256 blocks x 256 thr (4 waves). Block (bh,nb) owns b in [bh*32,+32),
// n in [nb*16,+16), FULL K=2048. W slice (16n x 2048k, split-bf16 hi+lo)
// in LDS forever (128 KB). h operand: double-buffered global pub buffer
// of bf16 MFMA-A fragments -> consumers load A-frags DIRECTLY
// global->VGPR (L2-dedup'd per XCD after the in-barrier acquire fence).
// Waves split K (4 x 512), cross-wave LDS reduce, fp32 register h
// update, astore out[t], publish bf16 h[t] to other parity. One gbar.
// =====================================================================
__global__ __launch_bounds__(256) void ctrnn_scan(
    const float* __restrict__ Whh, float* out,
    unsigned long long* __restrict__ pub, unsigned* slots)
{
  __shared__ __align__(16) uint4 Whi[4096];   // 64 KB
  __shared__ __align__(16) uint4 Wlo[4096];   // 64 KB
  __shared__ __align__(16) f32x4 Red[512];    // 8 KB
  __shared__ unsigned short Hs[32][16];       // 1 KB bf16 publish staging
  __shared__ unsigned go;                     // burner release flag

  const int tid = threadIdx.x, bid = blockIdx.x;
  const int nb = bid & 127, bh = bid >> 7;
  const int n0 = nb * 16, b0 = bh * 32;

  const int lane = tid & 63, wid = tid >> 6;
  const int fq = lane >> 4, fr = lane & 15;

  if (tid == 0) go = 0;

  // ---- stage W slice ONCE: rows n0..n0+16, all k, frag-packed hi/lo ----
  for (int s = tid; s < 4096; s += 256) {
    const int kcg = s >> 6, l = s & 63;
    const int n = n0 + (l & 15), k = kcg * 32 + (l >> 4) * 8;
    uint4 hi, lo;
    cvt8(&Whh[(size_t)n * H_DIM + k], hi, lo);
    Whi[s] = hi; Wlo[s] = lo;
  }

  // ---- ownership mapping (MFMA C layout: col=lane&15=n, row=b) ----
  const int bt = tid >> 7, jh = (tid >> 6) & 1, ln = tid & 63;
  const int rfr = ln & 15, rfq = ln >> 4;
  const int bl0 = bt * 16 + rfq * 4 + jh * 2;            // local b of 1st
  const size_t oa0 = (size_t)(b0 + bl0) * H_DIM + n0 + rfr;
  const size_t oa1 = oa0 + H_DIM;

  // fp32 h state in registers (h[0] = out[0], t=0 folded in xin_gemm)
  float h0 = out[oa0];
  float h1 = out[oa1];

  // ---- publish h[0] as bf16 frags to pub parity 0 ----
  Hs[bl0][rfr]     = (unsigned short)bf16_rne(h0);
  Hs[bl0 + 1][rfr] = (unsigned short)bf16_rne(h1);
  __syncthreads();   // also covers W staging + go init
  if (tid < 64) {
    const int b_l = tid & 31, h8 = tid >> 5;
    const uint4 frag = *(const uint4*)&Hs[b_l][h8 * 8];
    const size_t slot = (size_t)(nb * 2 + h8) * 64 + b0 + b_l;
    astoreU(&pub[slot * 2 + 0], ((const unsigned long long*)&frag)[0]);
    astoreU(&pub[slot * 2 + 1], ((const unsigned long long*)&frag)[1]);
  }

  const int baseA = wid * 4096 + fq * 64 + b0 + fr;  // slot idx, +kc*256
  const int baseB = wid * 1024;                      // +kc*64+lane

  for (int t = 1; t < T_DIM; ++t) {
    // prefetch xin BEFORE barrier (latency hides under the wait)
    const float xin0 = out[(size_t)t * BH + oa0];
    const float xin1 = out[(size_t)t * BH + oa1];
    asm volatile("" :: "v"(xin0), "v"(xin1));  // keep loads before gbar

    gbar(slots, t, bid, &go);  // vmcnt drain + early fence + burner waves

    const uint4* pr = (const uint4*)(pub + (size_t)((t - 1) & 1) * PUB_U64);

    // ---- GEMM: this wave covers k in [wid*512, +512) ----
    f32x4 acc0 = {0.f, 0.f, 0.f, 0.f}, acc1 = {0.f, 0.f, 0.f, 0.f};
    #pragma unroll
    for (int kc = 0; kc < 16; ++kc) {
      const uint4 a0 = pr[baseA + kc * 256];        // A-frag, btile 0
      const uint4 a1 = pr[baseA + kc * 256 + 16];   // A-frag, btile 1
      const uint4 bh4 = Whi[baseB + kc * 64 + lane];
      const uint4 bl4 = Wlo[baseB + kc * 64 + lane];
      acc0 = __builtin_amdgcn_mfma_f32_16x16x32_bf16(
          *(const bf16x8*)&a0, *(const bf16x8*)&bh4, acc0, 0, 0, 0);
      acc0 = __builtin_amdgcn_mfma_f32_16x16x32_bf16(
          *(const bf16x8*)&a0, *(const bf16x8*)&bl4, acc0, 0, 0, 0);
      acc1 = __builtin_amdgcn_mfma_f32_16x16x32_bf16(
          *(const bf16x8*)&a1, *(const bf16x8*)&bh4, acc1, 0, 0, 0);
      acc1 = __builtin_amdgcn_mfma_f32_16x16x32_bf16(
          *(const bf16x8*)&a1, *(const bf16x8*)&bl4, acc1, 0, 0, 0);
    }

    // ---- cross-wave K reduce ----
    Red[(wid * 2 + 0) * 64 + lane] = acc0;
    Red[(wid * 2 + 1) * 64 + lane] = acc1;
    __syncthreads();

    float s0 = 0.f, s1 = 0.f;
    #pragma unroll
    for (int w = 0; w < 4; ++w) {
      const float2 p = *(const float2*)(
          (const char*)&Red[(w * 2 + bt) * 64 + ln] + jh * 8);
      s0 += p.x; s1 += p.y;
    }

    // ---- leaky-relu update (fp32 register state) ----
    h0 = 0.99f * h0 + 0.01f * fmaxf(xin0 + s0, 0.f);
    h1 = 0.99f * h1 + 0.01f * fmaxf(xin1 + s1, 0.f);

    // ---- publish bf16 h[t] first (critical path), then out stores ----
    __syncthreads();   // Red reads done; safe to reuse Hs
    Hs[bl0][rfr]     = (unsigned short)bf16_rne(h0);
    Hs[bl0 + 1][rfr] = (unsigned short)bf16_rne(h1);
    __syncthreads();
    if (tid < 64) {
      const int b_l = tid & 31, h8 = tid >> 5;
      const uint4 frag = *(const uint4*)&Hs[b_l][h8 * 8];
      const size_t slot = (size_t)(nb * 2 + h8) * 64 + b0 + b_l;
      unsigned long long* pw =
          pub + (size_t)(t & 1) * PUB_U64 + slot * 2;
      astoreU(pw + 0, ((const unsigned long long*)&frag)[0]);
      astoreU(pw + 1, ((const unsigned long long*)&frag)[1]);
    }
    astore4(&out[(size_t)t * BH + oa0], h0);
    astore4(&out[(size_t)t * BH + oa1], h1);
    if (t == T_DIM - 1) {
      astore4(&out[(size_t)T_DIM * BH + oa0], h0);  // h_last
      astore4(&out[(size_t)T_DIM * BH + oa1], h1);
    }
    // next gbar's vmcnt(0) drains publishes before signaling
  }
}

// =====================================================================
extern "C" void kernel_launch(void* const* d_in, const int* in_sizes, int n_in,
                              void* d_out, int out_size, void* d_ws, size_t ws_size,
                              hipStream_t stream) {
  const float* x    = (const float*)d_in[0];
  const float* Wih  = (const float*)d_in[1];
  const float* bih  = (const float*)d_in[2];
  const float* Whh  = (const float*)d_in[3];
  const float* bhh  = (const float*)d_in[4];
  float* out = (float*)d_out;

  unsigned* slots = (unsigned*)d_ws;                          // 16KB + master
  unsigned long long* pub =
      (unsigned long long*)((char*)d_ws + 32768);             // 512 KB

  hipMemsetAsync(d_ws, 0, 32768, stream);  // reset slots+master every call

  xin_gemm<<<dim3(2048), dim3(256), 0, stream>>>(x, Wih, bih, bhh, out);
  ctrnn_scan<<<dim3(NBLK), dim3(256), 0, stream>>>(Whh, out, pub, slots);
}

// Round 11
// 1635.499 us; speedup vs baseline: 2.3394x; 2.1119x over previous
//
#include <hip/hip_runtime.h>

// Problem dims (fixed by setup_inputs): T=256, B=64, I=512, H=2048
#define T_DIM 256
#define B_DIM 64
#define I_DIM 512
#define H_DIM 2048
#define BH (B_DIM * H_DIM)      // 131072 floats per timestep slice
#define NBLK 256                // persistent grid: 1 block per CU
#define PUB_U64 32768           // one parity: 16384 slots * 2 u64 (256 KB)

typedef __attribute__((ext_vector_type(8))) short bf16x8;
typedef __attribute__((ext_vector_type(4))) float f32x4;

// ---------------------------------------------------------------------
// Agent-scope ops (validated R4-R10): relaxed sc-bit global ops are
// serviced at the device coherence point (MALL) — always coherent,
// never stale, no fences needed.
// ---------------------------------------------------------------------
__device__ __forceinline__ unsigned aloadU32(const unsigned* p) {
  return __hip_atomic_load(p, __ATOMIC_RELAXED, __HIP_MEMORY_SCOPE_AGENT);
}
__device__ __forceinline__ unsigned long long aload64(
    const unsigned long long* p) {
  return __hip_atomic_load(p, __ATOMIC_RELAXED, __HIP_MEMORY_SCOPE_AGENT);
}
__device__ __forceinline__ void astore4(float* p, float a) {
  union { unsigned u; float f; } c; c.f = a;
  __hip_atomic_store((unsigned*)p, c.u, __ATOMIC_RELAXED,
                     __HIP_MEMORY_SCOPE_AGENT);
}
__device__ __forceinline__ void astoreU(unsigned long long* p,
                                        unsigned long long v) {
  __hip_atomic_store(p, v, __ATOMIC_RELAXED, __HIP_MEMORY_SCOPE_AGENT);
}

// bf16 split helpers
__device__ __forceinline__ unsigned bf16_rne(float x) {
  union { float f; unsigned u; } c; c.f = x;
  return (c.u + 0x7FFFu + ((c.u >> 16) & 1u)) >> 16;
}
__device__ __forceinline__ float bf16_to_f(unsigned b) {
  union { float f; unsigned u; } c; c.u = b << 16; return c.f;
}
__device__ __forceinline__ void cvt_pair(float x0, float x1,
                                         unsigned& hi, unsigned& lo) {
  unsigned h0 = bf16_rne(x0), h1 = bf16_rne(x1);
  float r0 = x0 - bf16_to_f(h0), r1 = x1 - bf16_to_f(h1);
  unsigned l0 = bf16_rne(r0), l1 = bf16_rne(r1);
  hi = h0 | (h1 << 16);
  lo = l0 | (l1 << 16);
}
__device__ __forceinline__ void cvt8(const float* s, uint4& hi, uint4& lo) {
  float4 a = *(const float4*)s;
  float4 b = *(const float4*)(s + 4);
  cvt_pair(a.x, a.y, hi.x, lo.x);
  cvt_pair(a.z, a.w, hi.y, lo.y);
  cvt_pair(b.x, b.y, hi.z, lo.z);
  cvt_pair(b.z, b.w, hi.w, lo.w);
}

// =====================================================================
// Kernel A: xin = x @ W_ih^T + b_ih + b_hh  (rows m<64 fold t=0:
// out[0] = 0.01*relu(xin[0])).  Unchanged (fp32 VALU).
// =====================================================================
__global__ __launch_bounds__(256) void xin_gemm(
    const float* __restrict__ x, const float* __restrict__ Wih,
    const float* __restrict__ bih, const float* __restrict__ bhh,
    float* __restrict__ out)
{
  __shared__ __align__(16) float As[16][132];
  __shared__ __align__(16) float Bs[16][132];
  const int tid = threadIdx.x;
  const int nb = blockIdx.x & 15, mb = blockIdx.x >> 4;
  const int m0 = mb * 128, n0 = nb * 128;
  const int tx = tid & 15, ty = tid >> 4;

  float acc[8][8];
  #pragma unroll
  for (int i = 0; i < 8; ++i)
    #pragma unroll
    for (int j = 0; j < 8; ++j) acc[i][j] = 0.f;

  for (int k0 = 0; k0 < I_DIM; k0 += 16) {
    __syncthreads();
    {
      const int r = tid >> 1;
      #pragma unroll
      for (int c = 0; c < 2; ++c) {
        const int kq = (tid & 1) * 4 + c * 8;
        float4 va = *(const float4*)&x[(size_t)(m0 + r) * I_DIM + k0 + kq];
        As[kq + 0][r] = va.x; As[kq + 1][r] = va.y;
        As[kq + 2][r] = va.z; As[kq + 3][r] = va.w;
        float4 vb = *(const float4*)&Wih[(size_t)(n0 + r) * I_DIM + k0 + kq];
        Bs[kq + 0][r] = vb.x; Bs[kq + 1][r] = vb.y;
        Bs[kq + 2][r] = vb.z; Bs[kq + 3][r] = vb.w;
      }
    }
    __syncthreads();
    #pragma unroll 4
    for (int k = 0; k < 16; ++k) {
      float a[8], b[8];
      *(float4*)&a[0] = *(const float4*)&As[k][ty * 8];
      *(float4*)&a[4] = *(const float4*)&As[k][ty * 8 + 4];
      *(float4*)&b[0] = *(const float4*)&Bs[k][tx * 4];
      *(float4*)&b[4] = *(const float4*)&Bs[k][64 + tx * 4];
      #pragma unroll
      for (int i = 0; i < 8; ++i)
        #pragma unroll
        for (int j = 0; j < 8; ++j) acc[i][j] += a[i] * b[j];
    }
  }

  float bb[8];
  #pragma unroll
  for (int j = 0; j < 4; ++j) {
    bb[j]     = bih[n0 + tx * 4 + j]      + bhh[n0 + tx * 4 + j];
    bb[4 + j] = bih[n0 + 64 + tx * 4 + j] + bhh[n0 + 64 + tx * 4 + j];
  }
  #pragma unroll
  for (int i = 0; i < 8; ++i) {
    const int m = m0 + ty * 8 + i;
    float v[8];
    #pragma unroll
    for (int j = 0; j < 8; ++j) v[j] = acc[i][j] + bb[j];
    if (m < B_DIM) {
      #pragma unroll
      for (int j = 0; j < 8; ++j) v[j] = 0.01f * fmaxf(v[j], 0.f);
    }
    *(float4*)&out[(size_t)m * H_DIM + n0 + tx * 4] =
        make_float4(v[0], v[1], v[2], v[3]);
    *(float4*)&out[(size_t)m * H_DIM + n0 + 64 + tx * 4] =
        make_float4(v[4], v[5], v[6], v[7]);
  }
}

// =====================================================================
// Kernel B: BARRIER-FREE producer-consumer scan (R11).
// Insight: block (bh,nb) consumes h rows [bh*32,+32) — produced only by
// the 128 blocks sharing bh; wave wid needs just 32 producers
// nb' in [wid*32,+32).  Flags replace the grid barrier:
//   producer: publish h[t] frags -> vmcnt drain -> flag = t+1 (agent).
//   consumer wave: poll its 32 producer flags >= t, then GEMM.
// Double-buffer safety: entry at step t requires all group flags >= t,
// which proves every reader of parity (t&1)'s old data has advanced
// (skew <= 1 step).  Pub A-frags read with relaxed AGENT loads (always
// coherent) -> the per-step acquire fence is GONE.  xin/out normal
// reads are touch-once per launch (kernel-boundary invalidate covers
// graph replays; model validated by R6's passing fence+normal variant).
// Serial chain/step: publish-drain + flag-detect + pub-loads ~3 hops
// (was ~6-7 with the two-hop barrier + fence).
// =====================================================================
__global__ __launch_bounds__(256) void ctrnn_scan(
    const float* __restrict__ Whh, float* out,
    unsigned long long* __restrict__ pub, unsigned* slots)
{
  __shared__ __align__(16) uint4 Whi[4096];   // 64 KB
  __shared__ __align__(16) uint4 Wlo[4096];   // 64 KB
  __shared__ __align__(16) f32x4 Red[512];    // 8 KB
  __shared__ unsigned short Hs[32][16];       // 1 KB bf16 publish staging

  const int tid = threadIdx.x, bid = blockIdx.x;
  const int nb = bid & 127, bh = bid >> 7;
  const int n0 = nb * 16, b0 = bh * 32;

  const int lane = tid & 63, wid = tid >> 6;
  const int fq = lane >> 4, fr = lane & 15;

  // ---- stage W slice ONCE: rows n0..n0+16, all k, frag-packed hi/lo ----
  for (int s = tid; s < 4096; s += 256) {
    const int kcg = s >> 6, l = s & 63;
    const int n = n0 + (l & 15), k = kcg * 32 + (l >> 4) * 8;
    uint4 hi, lo;
    cvt8(&Whh[(size_t)n * H_DIM + k], hi, lo);
    Whi[s] = hi; Wlo[s] = lo;
  }

  // ---- ownership mapping (MFMA C layout: col=lane&15=n, row=b) ----
  const int bt = tid >> 7, jh = (tid >> 6) & 1, ln = tid & 63;
  const int rfr = ln & 15, rfq = ln >> 4;
  const int bl0 = bt * 16 + rfq * 4 + jh * 2;            // local b of 1st
  const size_t oa0 = (size_t)(b0 + bl0) * H_DIM + n0 + rfr;
  const size_t oa1 = oa0 + H_DIM;

  // fp32 h state in registers (h[0] = out[0], t=0 folded in xin_gemm)
  float h0 = out[oa0];
  float h1 = out[oa1];

  // ---- publish h[0] as bf16 frags to pub parity 0, then flag = 1 ----
  Hs[bl0][rfr]     = (unsigned short)bf16_rne(h0);
  Hs[bl0 + 1][rfr] = (unsigned short)bf16_rne(h1);
  __syncthreads();   // also covers W staging completion
  if (tid < 64) {
    const int b_l = tid & 31, h8 = tid >> 5;
    const uint4 frag = *(const uint4*)&Hs[b_l][h8 * 8];
    const size_t slot = (size_t)(nb * 2 + h8) * 64 + b0 + b_l;
    astoreU(&pub[slot * 2 + 0], ((const unsigned long long*)&frag)[0]);
    astoreU(&pub[slot * 2 + 1], ((const unsigned long long*)&frag)[1]);
  }
  asm volatile("s_waitcnt vmcnt(0)" ::: "memory");
  if (tid == 0)
    __hip_atomic_store(slots + (size_t)bid * 16, 1u, __ATOMIC_RELAXED,
                       __HIP_MEMORY_SCOPE_AGENT);

  // my wave's 32 producer flags: blocks (bh, wid*32 + 0..31)
  const unsigned* myflag =
      slots + (size_t)(bh * 128 + wid * 32 + (lane & 31)) * 16;

  const int baseA64 = (wid * 4096 + fq * 64 + b0 + fr) * 2;  // u64 units
  const int baseB = wid * 1024;                              // +kc*64+lane

  for (int t = 1; t < T_DIM; ++t) {
    // prefetch xin (normal load; touch-once line, latency hides in poll)
    const float xin0 = out[(size_t)t * BH + oa0];
    const float xin1 = out[(size_t)t * BH + oa1];
    asm volatile("" :: "v"(xin0), "v"(xin1));  // keep loads here

    // ---- per-wave flag poll: my 32 producers have published h[t-1] ----
    for (int it = 0; it < (1 << 17); ++it) {
      if (__all(aloadU32(myflag) >= (unsigned)t)) break;
      __builtin_amdgcn_s_sleep(1);
    }

    const unsigned long long* pr = pub + (size_t)((t - 1) & 1) * PUB_U64;

    // ---- GEMM: agent-load A-frags straight from MALL (no fence) ----
    f32x4 acc0 = {0.f, 0.f, 0.f, 0.f}, acc1 = {0.f, 0.f, 0.f, 0.f};
    #pragma unroll
    for (int kc = 0; kc < 16; ++kc) {
      union { unsigned long long u[2]; bf16x8 v; } a0c, a1c;
      a0c.u[0] = aload64(pr + baseA64 + kc * 512 + 0);
      a0c.u[1] = aload64(pr + baseA64 + kc * 512 + 1);
      a1c.u[0] = aload64(pr + baseA64 + kc * 512 + 32);
      a1c.u[1] = aload64(pr + baseA64 + kc * 512 + 33);
      const uint4 bh4 = Whi[baseB + kc * 64 + lane];
      const uint4 bl4 = Wlo[baseB + kc * 64 + lane];
      acc0 = __builtin_amdgcn_mfma_f32_16x16x32_bf16(
          a0c.v, *(const bf16x8*)&bh4, acc0, 0, 0, 0);
      acc0 = __builtin_amdgcn_mfma_f32_16x16x32_bf16(
          a0c.v, *(const bf16x8*)&bl4, acc0, 0, 0, 0);
      acc1 = __builtin_amdgcn_mfma_f32_16x16x32_bf16(
          a1c.v, *(const bf16x8*)&bh4, acc1, 0, 0, 0);
      acc1 = __builtin_amdgcn_mfma_f32_16x16x32_bf16(
          a1c.v, *(const bf16x8*)&bl4, acc1, 0, 0, 0);
    }

    // ---- cross-wave K reduce ----
    Red[(wid * 2 + 0) * 64 + lane] = acc0;
    Red[(wid * 2 + 1) * 64 + lane] = acc1;
    __syncthreads();

    float s0 = 0.f, s1 = 0.f;
    #pragma unroll
    for (int w = 0; w < 4; ++w) {
      const float2 p = *(const float2*)(
          (const char*)&Red[(w * 2 + bt) * 64 + ln] + jh * 8);
      s0 += p.x; s1 += p.y;
    }

    // ---- leaky-relu update (fp32 register state) ----
    h0 = 0.99f * h0 + 0.01f * fmaxf(xin0 + s0, 0.f);
    h1 = 0.99f * h1 + 0.01f * fmaxf(xin1 + s1, 0.f);

    // ---- output stores (not on the critical path) ----
    astore4(&out[(size_t)t * BH + oa0], h0);
    astore4(&out[(size_t)t * BH + oa1], h1);
    if (t == T_DIM - 1) {
      astore4(&out[(size_t)T_DIM * BH + oa0], h0);  // h_last
      astore4(&out[(size_t)T_DIM * BH + oa1], h1);
    }

    // ---- publish bf16 h[t] -> parity t&1, drain, flag = t+1 ----
    if (t < T_DIM - 1) {
      __syncthreads();   // Red reads done; safe to reuse Hs
      Hs[bl0][rfr]     = (unsigned short)bf16_rne(h0);
      Hs[bl0 + 1][rfr] = (unsigned short)bf16_rne(h1);
      __syncthreads();
      if (tid < 64) {
        const int b_l = tid & 31, h8 = tid >> 5;
        const uint4 frag = *(const uint4*)&Hs[b_l][h8 * 8];
        const size_t slot = (size_t)(nb * 2 + h8) * 64 + b0 + b_l;
        unsigned long long* pw =
            pub + (size_t)(t & 1) * PUB_U64 + slot * 2;
        astoreU(pw + 0, ((const unsigned long long*)&frag)[0]);
        astoreU(pw + 1, ((const unsigned long long*)&frag)[1]);
      }
      asm volatile("s_waitcnt vmcnt(0)" ::: "memory");
      if (tid == 0)
        __hip_atomic_store(slots + (size_t)bid * 16, (unsigned)(t + 1),
                           __ATOMIC_RELAXED, __HIP_MEMORY_SCOPE_AGENT);
    }
  }
}

// =====================================================================
extern "C" void kernel_launch(void* const* d_in, const int* in_sizes, int n_in,
                              void* d_out, int out_size, void* d_ws, size_t ws_size,
                              hipStream_t stream) {
  const float* x    = (const float*)d_in[0];
  const float* Wih  = (const float*)d_in[1];
  const float* bih  = (const float*)d_in[2];
  const float* Whh  = (const float*)d_in[3];
  const float* bhh  = (const float*)d_in[4];
  float* out = (float*)d_out;

  unsigned* slots = (unsigned*)d_ws;                          // 16 KB flags
  unsigned long long* pub =
      (unsigned long long*)((char*)d_ws + 32768);             // 512 KB

  hipMemsetAsync(d_ws, 0, 32768, stream);  // reset flags every call

  xin_gemm<<<dim3(2048), dim3(256), 0, stream>>>(x, Wih, bih, bhh, out);
  ctrnn_scan<<<dim3(NBLK), dim3(256), 0, stream>>>(Whh, out, pub, slots);
}